// Round 9
// baseline (43.078 us; speedup 1.0000x reference)
//
#include <hip/hip_runtime.h>
#include <stdint.h>

#define NE    7
#define DD    64
#define NDC   3
#define BLOCK 256
#define NFRAG 18        // W^T A-fragments: 8 (L1) + 8 (L2) + 2 (L3)

// d_ws layout (dwords):
#define WOFF  16        // packed weights: 7 * 18*64*4 = 32256 dwords
#define LOFF  32768     // per-expert index lists (prefilled with 0)
#define PAD   40960     // slots per expert (mean 37449, sigma ~180 -> +19 sigma)
#define K1ROWS 512
#define GRIDX 160       // x-blocks per expert
#define SEGS  2         // segments per block: GRIDX*SEGS*128 == PAD

typedef __fp16   half8 __attribute__((ext_vector_type(8)));
typedef float    f32x4 __attribute__((ext_vector_type(4)));
typedef uint32_t u32x4 __attribute__((ext_vector_type(4)));
typedef __fp16   h2_t  __attribute__((ext_vector_type(2)));

__device__ __forceinline__ uint32_t pkrtz(float a, float b) {
  h2_t h = __builtin_amdgcn_cvt_pkrtz(a, b);
  return __builtin_bit_cast(uint32_t, h);
}

__device__ __forceinline__ f32x4 mfma16(u32x4 a, u32x4 b, f32x4 c) {
  return __builtin_amdgcn_mfma_f32_16x16x32_f16(
      __builtin_bit_cast(half8, a), __builtin_bit_cast(half8, b), c, 0, 0, 0);
}

__device__ __forceinline__ u32x4 relu_pack(f32x4 lo, f32x4 hi) {
  u32x4 t = { pkrtz(fmaxf(lo[0],0.f), fmaxf(lo[1],0.f)),
              pkrtz(fmaxf(lo[2],0.f), fmaxf(lo[3],0.f)),
              pkrtz(fmaxf(hi[0],0.f), fmaxf(hi[1],0.f)),
              pkrtz(fmaxf(hi[2],0.f), fmaxf(hi[3],0.f)) };
  return t;
}

// ---- pack W^T into A-fragment layout (HW-verified R4) + prefill lists + zero hdr ----
__global__ __launch_bounds__(BLOCK) void pack_fill(
    const float* __restrict__ W1, const float* __restrict__ W2,
    const float* __restrict__ W3, uint32_t* __restrict__ ws) {
  const int b = blockIdx.x, tid = threadIdx.x;

  u32x4* lists4 = (u32x4*)(ws + LOFF);
  const int total4 = NE*PAD/4;
  u32x4 z = {0,0,0,0};
  for (int i = b*BLOCK + tid; i < total4; i += 64*BLOCK) lists4[i] = z;
  if (b == 63 && tid < WOFF) ws[tid] = 0;

  if (b >= NE) return;
  const int e = b;
  const float* Wl0 = W1 + e*DD*DD;
  const float* Wl1 = W2 + e*DD*DD;
  const float* Wl2 = W3 + e*DD*NDC;
  for (int idx = tid; idx < NFRAG*64; idx += BLOCK) {
    const int f = idx >> 6, l = idx & 63;
    int layer, fl;
    if (f < 8)       { layer = 0; fl = f; }
    else if (f < 16) { layer = 1; fl = f - 8; }
    else             { layer = 2; fl = f - 16; }
    const int nt = (layer < 2) ? (fl >> 1) : 0;
    const int ks = fl & 1;
    const int n  = nt*16 + (l & 15);
    const int g  = l >> 4;
    uint32_t dst[4];
    for (int d = 0; d < 4; ++d) {
      float v[2];
      for (int h = 0; h < 2; ++h) {
        const int kk = 16*(d>>1) + 4*g + 2*(d&1) + h;
        const int k  = 32*ks + kk;
        float val;
        if (layer == 0)      val = Wl0[k*DD + n];
        else if (layer == 1) val = Wl1[k*DD + n];
        else                 val = (n < NDC) ? Wl2[k*NDC + n] : 0.0f;
        v[h] = val;
      }
      dst[d] = pkrtz(v[0], v[1]);
    }
    uint32_t* p = ws + WOFF + ((size_t)(e*NFRAG + f)*64 + l)*4;
    p[0]=dst[0]; p[1]=dst[1]; p[2]=dst[2]; p[3]=dst[3];
  }
}

// ---- K1: expert compaction, ballot-aggregated ----
__global__ __launch_bounds__(BLOCK) void k1_scatter(const int* __restrict__ S,
                                                    uint32_t* __restrict__ ws) {
  __shared__ int lcnt[NE];
  __shared__ int gb[NE];
  __shared__ int ll[NE][K1ROWS];
  const int tid = threadIdx.x, lane = tid & 63;
  if (tid < NE) lcnt[tid] = 0;
  __syncthreads();
  const int base = blockIdx.x * K1ROWS;
  #pragma unroll
  for (int t = 0; t < K1ROWS/BLOCK; ++t) {
    const int row = base + t*BLOCK + tid;
    const int s = S[row];
    unsigned long long mk[NE];
    #pragma unroll
    for (int e = 0; e < NE; ++e) mk[e] = __ballot(s == e);
    int baseE = 0;
    if (lane < NE) {
      const int c = __popcll(mk[lane]);
      if (c) baseE = atomicAdd(&lcnt[lane], c);
    }
    const int mybase = __shfl(baseE, s, 64);
    unsigned long long mym = 0;
    #pragma unroll
    for (int e = 0; e < NE; ++e) if (s == e) mym = mk[e];
    const int pos = mybase + __popcll(mym & ((1ull << lane) - 1ull));
    ll[s][pos] = row;
  }
  __syncthreads();
  if (tid < NE) gb[tid] = atomicAdd((int*)ws + tid, lcnt[tid]);
  __syncthreads();
  int* lists = (int*)ws + LOFF;
  for (int e = 0; e < NE; ++e) {
    const int c = lcnt[e], g0 = gb[e];
    for (int i = tid; i < c; i += BLOCK) lists[(size_t)e*PAD + g0 + i] = ll[e][i];
  }
}

// ---- K2: af staged in LDS once per block; 2 segments per block; 1 pass/wave/segment ----
__global__ __launch_bounds__(BLOCK) void k2_main(
    const float* __restrict__ X, const uint32_t* __restrict__ ws,
    const float* __restrict__ b1, const float* __restrict__ b2,
    const float* __restrict__ b3,
    float* __restrict__ out, int B)
{
  __shared__ u32x4 afl[NFRAG*64];   // 18 KB

  const int e   = blockIdx.y;
  const int cn  = ((const int*)ws)[e];
  const int tid = threadIdx.x;
  const int wv = tid >> 6, lane = tid & 63;
  const int r15 = lane & 15, g = lane >> 4;

  const int* gidx = (const int*)ws + LOFF + (size_t)e*PAD;

  // p=0 list loads first: longest chain (list -> X) starts before staging
  const int rel0_0 = blockIdx.x*128 + wv*32;
  int rowj0[2];
  #pragma unroll
  for (int jt = 0; jt < 2; ++jt)
    rowj0[jt] = gidx[rel0_0 + jt*16 + r15];   // lists prefilled -> safe

  // stage expert's A-fragments to LDS (coalesced, overlaps list->X latency)
  const u32x4* wsrc = (const u32x4*)(ws + WOFF) + (size_t)e*NFRAG*64;
  for (int u = tid; u < NFRAG*64; u += BLOCK) afl[u] = wsrc[u];
  __syncthreads();

  const float* b1e = b1 + e*DD;
  const float* b2e = b2 + e*DD;
  const float bb0 = b3[e*NDC+0], bb1 = b3[e*NDC+1], bb2 = b3[e*NDC+2];

  #pragma unroll
  for (int p = 0; p < SEGS; ++p) {
    const int rel0 = (blockIdx.x + p*GRIDX)*128 + wv*32;
    if (rel0 >= cn) continue;

    int rowj[2];
    if (p == 0) { rowj[0] = rowj0[0]; rowj[1] = rowj0[1]; }
    else {
      #pragma unroll
      for (int jt = 0; jt < 2; ++jt)
        rowj[jt] = gidx[rel0 + jt*16 + r15];
    }

    // gather X -> B-fragments
    u32x4 xf[2][2];
    #pragma unroll
    for (int jt = 0; jt < 2; ++jt) {
      const float* xr = X + (size_t)rowj[jt]*DD;
      #pragma unroll
      for (int ks = 0; ks < 2; ++ks) {
        const float4 v0 = *(const float4*)(xr + 32*ks + 4*g);
        const float4 v1 = *(const float4*)(xr + 32*ks + 16 + 4*g);
        u32x4 t = { pkrtz(v0.x,v0.y), pkrtz(v0.z,v0.w),
                    pkrtz(v1.x,v1.y), pkrtz(v1.z,v1.w) };
        xf[jt][ks] = t;
      }
    }

    // Layer 1
    f32x4 c[4][2];
    #pragma unroll
    for (int nt = 0; nt < 4; ++nt) {
      const float4 bv = *(const float4*)(b1e + nt*16 + 4*g);
      const u32x4 a0 = afl[(nt*2+0)*64 + lane];
      const u32x4 a1 = afl[(nt*2+1)*64 + lane];
      #pragma unroll
      for (int jt = 0; jt < 2; ++jt) {
        f32x4 acc = { bv.x, bv.y, bv.z, bv.w };
        acc = mfma16(a0, xf[jt][0], acc);
        acc = mfma16(a1, xf[jt][1], acc);
        c[nt][jt] = acc;
      }
    }
    u32x4 hf[2][2];
    #pragma unroll
    for (int jt = 0; jt < 2; ++jt) {
      hf[jt][0] = relu_pack(c[0][jt], c[1][jt]);
      hf[jt][1] = relu_pack(c[2][jt], c[3][jt]);
    }

    // Layer 2
    #pragma unroll
    for (int nt = 0; nt < 4; ++nt) {
      const float4 bv = *(const float4*)(b2e + nt*16 + 4*g);
      const u32x4 a0 = afl[(8 + nt*2+0)*64 + lane];
      const u32x4 a1 = afl[(8 + nt*2+1)*64 + lane];
      #pragma unroll
      for (int jt = 0; jt < 2; ++jt) {
        f32x4 acc = { bv.x, bv.y, bv.z, bv.w };
        acc = mfma16(a0, hf[jt][0], acc);
        acc = mfma16(a1, hf[jt][1], acc);
        c[nt][jt] = acc;
      }
    }
    u32x4 h2f[2][2];
    #pragma unroll
    for (int jt = 0; jt < 2; ++jt) {
      h2f[jt][0] = relu_pack(c[0][jt], c[1][jt]);
      h2f[jt][1] = relu_pack(c[2][jt], c[3][jt]);
    }

    // Layer 3 + softmax
    const u32x4 a30 = afl[16*64 + lane];
    const u32x4 a31 = afl[17*64 + lane];
    #pragma unroll
    for (int jt = 0; jt < 2; ++jt) {
      f32x4 acc = { bb0, bb1, bb2, 0.f };
      acc = mfma16(a30, h2f[jt][0], acc);
      acc = mfma16(a31, h2f[jt][1], acc);
      const int rel = rel0 + jt*16 + r15;
      if (g == 0 && rel < cn) {
        const int row = rowj[jt];
        const float l0 = acc[0], l1 = acc[1], l2 = acc[2];
        const float mx  = fmaxf(l0, fmaxf(l1, l2));
        const float p0  = __expf(l0 - mx);
        const float p1  = __expf(l1 - mx);
        const float p2  = __expf(l2 - mx);
        const float inv = 1.0f / (p0 + p1 + p2);
        float* o = out + (size_t)row*3;
        o[0] = l0; o[1] = l1; o[2] = l2;
        float* pr = out + (size_t)B*3 + (size_t)row*3;
        pr[0] = p0*inv; pr[1] = p1*inv; pr[2] = p2*inv;
      }
    }
  }
}

extern "C" void kernel_launch(void* const* d_in, const int* in_sizes, int n_in,
                              void* d_out, int out_size, void* d_ws, size_t ws_size,
                              hipStream_t stream)
{
  const float* X  = (const float*)d_in[0];
  const int*   S  = (const int*)d_in[1];
  const float* W1 = (const float*)d_in[2];
  const float* B1 = (const float*)d_in[3];
  const float* W2 = (const float*)d_in[4];
  const float* B2 = (const float*)d_in[5];
  const float* W3 = (const float*)d_in[6];
  const float* B3 = (const float*)d_in[7];
  float* out = (float*)d_out;
  uint32_t* ws = (uint32_t*)d_ws;

  const int B = in_sizes[0] / DD;   // 262144

  pack_fill<<<64, BLOCK, 0, stream>>>(W1, W2, W3, ws);
  k1_scatter<<<B / K1ROWS, BLOCK, 0, stream>>>(S, ws);
  k2_main<<<dim3(GRIDX, NE), BLOCK, 0, stream>>>(X, ws, B1, B2, B3, out, B);
}

// Round 10
// 36.864 us; speedup vs baseline: 1.1686x; 1.1686x over previous
//
#include <hip/hip_runtime.h>
#include <stdint.h>

#define NE    7
#define DD    64
#define NDC   3
#define BLOCK 256
#define ROWS  256       // rows per block (B = 1024 * 256 exactly)
#define NFRAG 18        // W^T A-fragments: 8 (L1) + 8 (L2) + 2 (L3)

typedef __fp16   half8 __attribute__((ext_vector_type(8)));
typedef float    f32x4 __attribute__((ext_vector_type(4)));
typedef uint32_t u32x4 __attribute__((ext_vector_type(4)));
typedef uint32_t u32x2 __attribute__((ext_vector_type(2)));
typedef __fp16   h2_t  __attribute__((ext_vector_type(2)));

__device__ __forceinline__ uint32_t pkrtz(float a, float b) {
  h2_t h = __builtin_amdgcn_cvt_pkrtz(a, b);
  return __builtin_bit_cast(uint32_t, h);
}

__device__ __forceinline__ f32x4 mfma16(u32x4 a, u32x4 b, f32x4 c) {
  return __builtin_amdgcn_mfma_f32_16x16x32_f16(
      __builtin_bit_cast(half8, a), __builtin_bit_cast(half8, b), c, 0, 0, 0);
}

__device__ __forceinline__ u32x4 relu_pack(f32x4 lo, f32x4 hi) {
  u32x4 t = { pkrtz(fmaxf(lo[0],0.f), fmaxf(lo[1],0.f)),
              pkrtz(fmaxf(lo[2],0.f), fmaxf(lo[3],0.f)),
              pkrtz(fmaxf(hi[0],0.f), fmaxf(hi[1],0.f)),
              pkrtz(fmaxf(hi[2],0.f), fmaxf(hi[3],0.f)) };
  return t;
}

// ---- pack W^T into A-fragment layout (HW-verified R4) ----
// lane l: row n = 16*nt + (l&15); dword d, half h: kk = 16*(d>>1)+4*(l>>4)+2*(d&1)+h;
// k = 32*ks + kk; value = W[k][n]  (W row-major [k][n]).
__global__ __launch_bounds__(BLOCK) void pack_w(
    const float* __restrict__ W1, const float* __restrict__ W2,
    const float* __restrict__ W3, uint32_t* __restrict__ ws) {
  const int e = blockIdx.x;
  const float* Wl0 = W1 + e*DD*DD;
  const float* Wl1 = W2 + e*DD*DD;
  const float* Wl2 = W3 + e*DD*NDC;
  for (int idx = threadIdx.x; idx < NFRAG*64; idx += BLOCK) {
    const int f = idx >> 6, l = idx & 63;
    int layer, fl;
    if (f < 8)       { layer = 0; fl = f; }
    else if (f < 16) { layer = 1; fl = f - 8; }
    else             { layer = 2; fl = f - 16; }
    const int nt = (layer < 2) ? (fl >> 1) : 0;
    const int ks = fl & 1;
    const int n  = nt*16 + (l & 15);
    const int g  = l >> 4;
    uint32_t dst[4];
    for (int d = 0; d < 4; ++d) {
      float v[2];
      for (int h = 0; h < 2; ++h) {
        const int kk = 16*(d>>1) + 4*g + 2*(d&1) + h;
        const int k  = 32*ks + kk;
        float val;
        if (layer == 0)      val = Wl0[k*DD + n];
        else if (layer == 1) val = Wl1[k*DD + n];
        else                 val = (n < NDC) ? Wl2[k*NDC + n] : 0.0f;
        v[h] = val;
      }
      dst[d] = pkrtz(v[0], v[1]);
    }
    uint32_t* p = ws + ((size_t)(e*NFRAG + f)*64 + l)*4;
    p[0]=dst[0]; p[1]=dst[1]; p[2]=dst[2]; p[3]=dst[3];
  }
}

// ---- fused: coalesced X stream -> LDS sort -> grouped MFMA, all in one block ----
__global__ __launch_bounds__(BLOCK, 3) void fused(
    const float* __restrict__ X, const int* __restrict__ S,
    const u32x4* __restrict__ wf,
    const float* __restrict__ b1, const float* __restrict__ b2,
    const float* __restrict__ b3,
    float* __restrict__ out, int B)
{
  __shared__ uint32_t pk[ROWS*32];   // 32 KB packed fp16 fragment store (slot-swizzled)
  __shared__ uint16_t srt[ROWS];     // expert-sorted local row list
  __shared__ int wcnt[4][NE];
  __shared__ int woff[4][NE];
  __shared__ int cnt[NE];

  const int tid  = threadIdx.x;
  const int wv   = tid >> 6, lane = tid & 63;
  const int r15  = lane & 15, g = lane >> 4;
  const int base = blockIdx.x * ROWS;

  // ---- A1: route ballots ----
  const int e_i = S[base + tid];
  unsigned long long mk[NE];
  #pragma unroll
  for (int e = 0; e < NE; ++e) mk[e] = __ballot(e_i == e);
  int myprefix = 0;
  #pragma unroll
  for (int e = 0; e < NE; ++e)
    if (e_i == e) myprefix = __popcll(mk[e] & ((1ull << lane) - 1ull));
  if (lane < NE) wcnt[wv][lane] = __popcll(mk[lane]);
  __syncthreads();

  // ---- A2 (tid0 serial 28-scan) overlapped with B (X -> LDS pack, 1-KB streams) ----
  if (tid == 0) {
    int acc = 0;
    for (int e = 0; e < NE; ++e) {
      const int s0 = acc;
      for (int w = 0; w < 4; ++w) { woff[w][e] = acc; acc += wcnt[w][e]; }
      cnt[e] = acc - s0;
    }
  }
  {
    const float4* Xb = (const float4*)(X + (size_t)base * DD);
    const int q     = lane & 15;          // float4 index within row
    const int rsub  = lane >> 4;          // row within 4-row chunk
    const int ksq   = q >> 3, gq = q & 3, hq = (q >> 2) & 1;
    const int slotq = 4*ksq + gq;
    #pragma unroll
    for (int it = 0; it < 16; ++it) {
      const int r = wv*64 + it*4 + rsub;
      const float4 v = Xb[r*16 + q];      // lane<->byte: perfect 1-KB contiguous per instr
      u32x2 w2 = { pkrtz(v.x, v.y), pkrtz(v.z, v.w) };
      *(u32x2*)&pk[r*32 + ((slotq ^ (r & 7)) << 2) + hq*2] = w2;
    }
  }
  __syncthreads();

  // ---- A3: scatter sorted list ----
  srt[woff[wv][e_i] + myprefix] = (uint16_t)tid;
  __syncthreads();

  // ---- C: grouped MFMA passes (waves round-robin over pass list) ----
  int pst[NE + 1];
  {
    int tp = 0;
    #pragma unroll
    for (int e = 0; e < NE; ++e) { pst[e] = tp; tp += (cnt[e] + 31) >> 5; }
    pst[NE] = tp;
  }

  for (int p = wv; p < pst[NE]; p += 4) {
    int e = 0;
    #pragma unroll
    for (int q2 = 1; q2 < NE; ++q2) if (p >= pst[q2]) e = q2;
    const int ch    = p - pst[e];
    const int m     = min(32, cnt[e] - ch*32);
    const int sbase = woff[0][e] + ch*32;

    // resident A-fragments for this pass: 18 fat 1-KB L2-hot loads
    const u32x4* wse = wf + (size_t)e*NFRAG*64;
    u32x4 af[NFRAG];
    #pragma unroll
    for (int f = 0; f < NFRAG; ++f) af[f] = wse[f*64 + lane];

    #pragma unroll 1
    for (int jt = 0; jt < 2; ++jt) {
      const int idx16 = min(jt*16 + r15, m - 1);
      const int lr    = srt[sbase + idx16];

      // B-fragments from LDS (slot-swizzled b128, random-row ~2-way banks)
      const u32x4 xf0 = *(const u32x4*)&pk[lr*32 + (((g    ) ^ (lr & 7)) << 2)];
      const u32x4 xf1 = *(const u32x4*)&pk[lr*32 + (((4 + g) ^ (lr & 7)) << 2)];

      // Layer 1
      f32x4 c[4];
      #pragma unroll
      for (int nt = 0; nt < 4; ++nt) {
        const float4 bv = *(const float4*)(b1 + e*DD + nt*16 + 4*g);
        f32x4 acc = { bv.x, bv.y, bv.z, bv.w };
        acc = mfma16(af[nt*2 + 0], xf0, acc);
        acc = mfma16(af[nt*2 + 1], xf1, acc);
        c[nt] = acc;
      }
      const u32x4 h0 = relu_pack(c[0], c[1]);
      const u32x4 h1 = relu_pack(c[2], c[3]);

      // Layer 2
      #pragma unroll
      for (int nt = 0; nt < 4; ++nt) {
        const float4 bv = *(const float4*)(b2 + e*DD + nt*16 + 4*g);
        f32x4 acc = { bv.x, bv.y, bv.z, bv.w };
        acc = mfma16(af[8 + nt*2 + 0], h0, acc);
        acc = mfma16(af[8 + nt*2 + 1], h1, acc);
        c[nt] = acc;
      }
      const u32x4 t0 = relu_pack(c[0], c[1]);
      const u32x4 t1 = relu_pack(c[2], c[3]);

      // Layer 3 + softmax (lanes g==0 hold classes 0..2 of their row)
      f32x4 acc = { b3[e*NDC + 0], b3[e*NDC + 1], b3[e*NDC + 2], 0.f };
      acc = mfma16(af[16], t0, acc);
      acc = mfma16(af[17], t1, acc);

      if (g == 0 && (jt*16 + r15) < m) {
        const int row = base + lr;
        const float l0 = acc[0], l1 = acc[1], l2 = acc[2];
        const float mx  = fmaxf(l0, fmaxf(l1, l2));
        const float p0  = __expf(l0 - mx);
        const float p1  = __expf(l1 - mx);
        const float p2  = __expf(l2 - mx);
        const float inv = 1.0f / (p0 + p1 + p2);
        float* o = out + (size_t)row*3;
        o[0] = l0; o[1] = l1; o[2] = l2;
        float* pr = out + (size_t)B*3 + (size_t)row*3;
        pr[0] = p0*inv; pr[1] = p1*inv; pr[2] = p2*inv;
      }
    }
  }
}

extern "C" void kernel_launch(void* const* d_in, const int* in_sizes, int n_in,
                              void* d_out, int out_size, void* d_ws, size_t ws_size,
                              hipStream_t stream)
{
  const float* X  = (const float*)d_in[0];
  const int*   S  = (const int*)d_in[1];
  const float* W1 = (const float*)d_in[2];
  const float* B1 = (const float*)d_in[3];
  const float* W2 = (const float*)d_in[4];
  const float* B2 = (const float*)d_in[5];
  const float* W3 = (const float*)d_in[6];
  const float* B3 = (const float*)d_in[7];
  float* out = (float*)d_out;
  uint32_t* ws = (uint32_t*)d_ws;

  const int B = in_sizes[0] / DD;   // 262144

  pack_w<<<NE, BLOCK, 0, stream>>>(W1, W2, W3, ws);
  fused<<<B / ROWS, BLOCK, 0, stream>>>(X, S, (const u32x4*)ws,
                                        B1, B2, B3, out, B);
}